// Round 2
// baseline (221.570 us; speedup 1.0000x reference)
//
#include <hip/hip_runtime.h>
#include <math.h>

// B=32, S=4096, D=256  (fp32). MAX_LEN=5000.
// out[b,s,d] = nodes[b,s,d] + (s <= num_nodes[b] ? pe[(s-num_nodes[b]) mod 5000, d] : 0)
// pe[p, 2k]   = sin(p * div[k])
// pe[p, 2k+1] = cos(p * div[k]),  div[k] = exp2(-log2(10000) * 2k / 256)
//
// sin/cos computed in the REVOLUTION domain with explicit fract range-reduction,
// then native v_sin_f32 / v_cos_f32 (valid on [0,1) revolutions). This avoids
// libm sincosf's Payne-Hanek slow path which made R0 5x off the memory roofline.

__global__ __launch_bounds__(256) void rpe_kernel(const float* __restrict__ nodes,
                                                  const int* __restrict__ num_nodes,
                                                  float* __restrict__ out) {
    const int tid = blockIdx.x * blockDim.x + threadIdx.x;  // one float4 per thread
    const int d4 = tid & 63;           // float4 index within row (64 per row)
    const int s  = (tid >> 6) & 4095;  // sequence position
    const int b  = tid >> 18;          // batch

    const int nn = num_nodes[b];       // wave-uniform (one wave == one row)

    float4 v = reinterpret_cast<const float4*>(nodes)[tid];

    if (s <= nn) {                     // wave-uniform branch (one wave == one row)
        int r = s - nn;                // r in (-4096, 0]
        int p = (r < 0) ? r + 5000 : r;  // Python mod semantics
        const float pf = (float)p;

        // this float4 covers d = 4*d4 .. 4*d4+3 -> sin/cos pairs 2k = 4*d4, 4*d4+2
        // f[k] = div[k] / (2*pi)  (revolutions per unit position)
        const float cexp   = -0.051905126482062035f;  // -log2(10000)/256
        const float inv2pi = 0.15915494309189535f;
        const float f0 = exp2f(cexp * (float)(4 * d4)) * inv2pi;
        const float f1 = exp2f(cexp * (float)(4 * d4 + 2)) * inv2pi;

        float r0 = pf * f0;  r0 -= floorf(r0);   // [0,1) revolutions
        float r1 = pf * f1;  r1 -= floorf(r1);

        v.x += __builtin_amdgcn_sinf(r0);   // v_sin_f32: sin(2*pi*r0)
        v.y += __builtin_amdgcn_cosf(r0);
        v.z += __builtin_amdgcn_sinf(r1);
        v.w += __builtin_amdgcn_cosf(r1);
    }

    reinterpret_cast<float4*>(out)[tid] = v;
}

extern "C" void kernel_launch(void* const* d_in, const int* in_sizes, int n_in,
                              void* d_out, int out_size, void* d_ws, size_t ws_size,
                              hipStream_t stream) {
    const float* nodes     = (const float*)d_in[0];
    const int*   num_nodes = (const int*)d_in[1];
    float*       out       = (float*)d_out;

    // total float4 elements: 32*4096*256/4 = 8388608 -> 32768 blocks of 256
    const int total4 = out_size / 4;
    const int block  = 256;
    const int grid   = (total4 + block - 1) / block;

    rpe_kernel<<<grid, block, 0, stream>>>(nodes, num_nodes, out);
}

// Round 3
// 218.591 us; speedup vs baseline: 1.0136x; 1.0136x over previous
//
#include <hip/hip_runtime.h>
#include <math.h>

// B=32, S=4096, D=256  (fp32). MAX_LEN=5000.
// out[b,s,d] = nodes[b,s,d] + (s <= num_nodes[b] ? pe[(s-num_nodes[b]) mod 5000, d] : 0)
// pe[p, 2k]   = sin(p * div[k]),  pe[p, 2k+1] = cos(p * div[k])
// div[k] = exp2(-log2(10000) * 2k / 256)
//
// Memory-bound: 134 MB read + 134 MB write, zero reuse. PE recomputed on the
// fly (revolution-domain range reduction + native v_sin/cos_f32, ~4 us VALU
// chip-wide, hidden). This round: nontemporal load/store hints to skip
// L2/LLC allocate/evict on the streamed data.

typedef float v4f __attribute__((ext_vector_type(4)));

__global__ __launch_bounds__(256) void rpe_kernel(const float* __restrict__ nodes,
                                                  const int* __restrict__ num_nodes,
                                                  float* __restrict__ out) {
    const int tid = blockIdx.x * blockDim.x + threadIdx.x;  // one float4 per thread
    const int d4 = tid & 63;           // float4 index within row (64 per row)
    const int s  = (tid >> 6) & 4095;  // sequence position
    const int b  = tid >> 18;          // batch

    const int nn = num_nodes[b];       // wave-uniform (one wave == one row)

    v4f v = __builtin_nontemporal_load(reinterpret_cast<const v4f*>(nodes) + tid);

    if (s <= nn) {                     // wave-uniform branch (one wave == one row)
        int r = s - nn;                // r in (-4096, 0]
        int p = (r < 0) ? r + 5000 : r;  // Python mod semantics
        const float pf = (float)p;

        // this float4 covers d = 4*d4 .. 4*d4+3 -> sin/cos pairs 2k = 4*d4, 4*d4+2
        // f[k] = div[k] / (2*pi)  (revolutions per unit position)
        const float cexp   = -0.051905126482062035f;  // -log2(10000)/256
        const float inv2pi = 0.15915494309189535f;
        const float f0 = exp2f(cexp * (float)(4 * d4)) * inv2pi;
        const float f1 = exp2f(cexp * (float)(4 * d4 + 2)) * inv2pi;

        float r0 = pf * f0;  r0 -= floorf(r0);   // [0,1) revolutions
        float r1 = pf * f1;  r1 -= floorf(r1);

        v.x += __builtin_amdgcn_sinf(r0);   // v_sin_f32: sin(2*pi*r0)
        v.y += __builtin_amdgcn_cosf(r0);
        v.z += __builtin_amdgcn_sinf(r1);
        v.w += __builtin_amdgcn_cosf(r1);
    }

    __builtin_nontemporal_store(v, reinterpret_cast<v4f*>(out) + tid);
}

extern "C" void kernel_launch(void* const* d_in, const int* in_sizes, int n_in,
                              void* d_out, int out_size, void* d_ws, size_t ws_size,
                              hipStream_t stream) {
    const float* nodes     = (const float*)d_in[0];
    const int*   num_nodes = (const int*)d_in[1];
    float*       out       = (float*)d_out;

    // total float4 elements: 32*4096*256/4 = 8388608 -> 32768 blocks of 256
    const int total4 = out_size / 4;
    const int block  = 256;
    const int grid   = (total4 + block - 1) / block;

    rpe_kernel<<<grid, block, 0, stream>>>(nodes, num_nodes, out);
}